// Round 4
// baseline (89.700 us; speedup 1.0000x reference)
//
#include <hip/hip_runtime.h>

#define BLOCK 8
#define NGRID 512

typedef float v2f __attribute__((ext_vector_type(2)));

static __device__ __forceinline__ v2f splat(float x) { v2f r; r.x = x; r.y = x; return r; }

// ---------------------------------------------------------------------------
// Compile-time replication of
//   np.random.RandomState(0).choice(np.array([1.0,3.0],f32), size=(512,8))
// (MT19937 legacy scalar seeding, one 32-bit draw per value, value = draw&1).
// Bit i of pattern byte = element i: g[i] = bit ? 3.0f : 1.0f.
// Dedup (first occurrence) is argmax-neutral. kenc = 255 - dedup_index, so
// "ties -> max kenc" == numpy first-max. Scan order = bit-reversed ascending
// (maximizes shared low-bit spine prefixes); selection is order-independent.
// ---------------------------------------------------------------------------
struct Sched {
  int nd;                      // distinct patterns (~222)
  unsigned char kpat[256];     // kenc -> pattern byte (epilogue gather)
  unsigned char dfs_pat[256];  // scan ordinal -> pattern byte
  unsigned char dfs_ken[256];  // scan ordinal -> kenc
  unsigned char lowbit[256];   // ordinal -> lowest differing bit vs prev (0 for j=0)
  unsigned char csn[32];       // chunk -> member count (chunks of 8)
  unsigned char cslot[32][8];  // chunk, i -> slot (ordinal & 7), kenc-ascending
  unsigned char cken[32][8];   // chunk, i -> kenc,                kenc-ascending
};

constexpr unsigned char bitrev8c(unsigned v) {
  unsigned r = 0;
  for (int i = 0; i < 8; ++i) r |= ((v >> i) & 1u) << (7 - i);
  return (unsigned char)r;
}
constexpr int popcount8c(int v) {
  int p = 0;
  for (int i = 0; i < 8; ++i) p += (v >> i) & 1;
  return p;
}
constexpr int ctz8c(int v) {
  for (int i = 0; i < 8; ++i) if ((v >> i) & 1) return i;
  return 0;
}

constexpr Sched make_sched() {
  Sched t{};
  bool exists[256] = {};
  unsigned char kenc[256] = {};
  // --- MT19937, numpy legacy scalar seed 0 ---
  unsigned mt[624] = {};
  {
    unsigned s = 0u;
    for (int i = 0; i < 624; ++i) {
      mt[i] = s;
      s = 1812433253u * (s ^ (s >> 30)) + (unsigned)(i + 1);
    }
  }
  int pos = 624;
  int nd = 0;
  for (int j = 0; j < NGRID; ++j) {
    unsigned char b = 0;
    for (int i = 0; i < BLOCK; ++i) {
      if (pos == 624) {
        for (int k = 0; k < 624; ++k) {
          int k1 = (k + 1 < 624) ? k + 1 : 0;
          int k397 = (k + 397 < 624) ? k + 397 : k + 397 - 624;
          unsigned y = (mt[k] & 0x80000000u) | (mt[k1] & 0x7fffffffu);
          unsigned v = mt[k397] ^ (y >> 1);
          if (y & 1u) v ^= 0x9908b0dfu;
          mt[k] = v;
        }
        pos = 0;
      }
      unsigned y = mt[pos++];
      y ^= y >> 11;
      y ^= (y << 7) & 0x9d2c5680u;
      y ^= (y << 15) & 0xefc60000u;
      y ^= y >> 18;
      if (y & 1u) b |= (unsigned char)(1u << i);
    }
    if (!exists[b]) {
      exists[b] = true;
      kenc[b] = (unsigned char)(255 - nd);
      t.kpat[255 - nd] = b;
      ++nd;
    }
  }
  t.nd = nd;
  // --- scan order: bit-reversed ascending ---
  int m = 0;
  for (int r = 0; r < 256; ++r) {
    unsigned char b = bitrev8c((unsigned)r);
    if (exists[b]) {
      t.dfs_pat[m] = b;
      t.dfs_ken[m] = kenc[b];
      ++m;
    }
  }
  t.lowbit[0] = 0;
  for (int j = 1; j < nd; ++j)
    t.lowbit[j] = (unsigned char)ctz8c(t.dfs_pat[j] ^ t.dfs_pat[j - 1]);
  // --- chunks of 8, members sorted by kenc ascending (insertion sort) ---
  int nc = (nd + 7) / 8;
  for (int c = 0; c < nc; ++c) {
    int n = nd - 8 * c; if (n > 8) n = 8;
    t.csn[c] = (unsigned char)n;
    unsigned char sl[8] = {}, ke[8] = {};
    for (int i = 0; i < n; ++i) { sl[i] = (unsigned char)i; ke[i] = t.dfs_ken[8 * c + i]; }
    for (int i = 1; i < n; ++i) {
      unsigned char ks = ke[i], ss = sl[i];
      int p = i - 1;
      while (p >= 0 && ke[p] > ks) { ke[p + 1] = ke[p]; sl[p + 1] = sl[p]; --p; }
      ke[p + 1] = ks; sl[p + 1] = ss;
    }
    for (int i = 0; i < n; ++i) { t.cslot[c][i] = sl[i]; t.cken[c][i] = ke[i]; }
  }
  return t;
}

constexpr Sched SC = make_sched();
constexpr int ND = SC.nd;
static_assert(ND > 0 && ND <= 256, "sanity");

// epilogue gather table: kenc -> pattern byte (L1-resident)
__device__ __constant__ const unsigned char g_pat[256] = {
#define P1(z) SC.kpat[z]
#define P8(z) P1(z), P1(z+1), P1(z+2), P1(z+3), P1(z+4), P1(z+5), P1(z+6), P1(z+7)
#define P64(z) P8(z), P8(z+8), P8(z+16), P8(z+24), P8(z+32), P8(z+40), P8(z+48), P8(z+56)
    P64(0), P64(64), P64(128), P64(192)
#undef P64
#undef P8
#undef P1
};

// ---------------------------------------------------------------------------
// One scan step (ordinal J). Spine sp[l] = dot of low-l bits' chain; leaf:
// sc = fl32(fl32(d*d)/norm), bit-identical to numpy (exact pow2 scale or
// Markstein CR division). Scores buffered 8 at a time; chunk-max + kenc-
// ordered eq-scan recovers "max score, ties -> min original k" exactly.
// ---------------------------------------------------------------------------
template <int J>
struct Step {
  static __device__ __forceinline__ void run(const v2f (&apk)[8], v2f (&sp)[9],
                                             v2f (&scs)[8], v2f &gb, int &gk0, int &gk1) {
    constexpr int pat = SC.dfs_pat[J];
    constexpr int p0 = (J == 0) ? 0 : SC.lowbit[J];
#pragma unroll
    for (int l = 0; l < 8; ++l) {
      if (l >= p0) {
        if ((pat >> l) & 1)
          sp[l + 1] = __builtin_elementwise_fma(apk[l], splat(3.0f), sp[l]);
        else
          sp[l + 1] = sp[l] + apk[l];
      }
    }
    v2f d = sp[8];
    v2f dd = d * d;
    constexpr int pc = popcount8c(pat);
    v2f sc;
    if constexpr (pc == 0)      sc = dd * splat(0.125f);     // /8  exact
    else if constexpr (pc == 1) sc = dd * splat(0.0625f);    // /16 exact
    else if constexpr (pc == 3) sc = dd * splat(0.03125f);   // /32 exact
    else if constexpr (pc == 7) sc = dd * splat(0.015625f);  // /64 exact
    else {
      constexpr float nf = (float)(8 * (1 + pc));
      constexpr float rcf = 1.0f / nf;
      v2f q0 = dd * splat(rcf);
      v2f r = __builtin_elementwise_fma(splat(-nf), q0, dd);  // exact residual
      sc = __builtin_elementwise_fma(r, splat(rcf), q0);      // == fl32(dd/nf)
    }
    scs[J & 7] = sc;

    if constexpr (((J & 7) == 7) || (J == ND - 1)) {
      constexpr int c = J >> 3;
      constexpr int n = SC.csn[c];
      v2f cm = scs[0];
#pragma unroll
      for (int i = 1; i < n; ++i) cm = __builtin_elementwise_max(cm, scs[i]);
      int ck0 = 0, ck1 = 0;
#pragma unroll
      for (int i = 0; i < n; ++i) {  // kenc ascending: last write = min k
        ck0 = (scs[SC.cslot[c][i]].x == cm.x) ? (int)SC.cken[c][i] : ck0;
        ck1 = (scs[SC.cslot[c][i]].y == cm.y) ? (int)SC.cken[c][i] : ck1;
      }
      bool r0 = (cm.x > gb.x) || ((cm.x == gb.x) && (ck0 > gk0));
      bool r1 = (cm.y > gb.y) || ((cm.y == gb.y) && (ck1 > gk1));
      gb.x = r0 ? cm.x : gb.x;  gk0 = r0 ? ck0 : gk0;
      gb.y = r1 ? cm.y : gb.y;  gk1 = r1 ? ck1 : gk1;
    }
    if constexpr (J + 1 < ND) Step<J + 1>::run(apk, sp, scs, gb, gk0, gk1);
  }
};

__global__ __launch_bounds__(256, 4) void _IQ2XSQuantWeight_12945031430379_kernel(
    const float* __restrict__ w, float* __restrict__ out, int nb) {
  int t = blockIdx.x * blockDim.x + threadIdx.x;
  int half = nb >> 1;
  if (t >= half) return;

  const float4* wp0 = reinterpret_cast<const float4*>(w) + (size_t)2 * t;
  const float4* wp1 = reinterpret_cast<const float4*>(w) + (size_t)2 * (t + half);
  float4 A0 = wp0[0], A1 = wp0[1];
  float4 B0 = wp1[0], B1 = wp1[1];
  float wv0[BLOCK] = {A0.x, A0.y, A0.z, A0.w, A1.x, A1.y, A1.z, A1.w};
  float wv1[BLOCK] = {B0.x, B0.y, B0.z, B0.w, B1.x, B1.y, B1.z, B1.w};

  v2f apk[8];
#pragma unroll
  for (int i = 0; i < BLOCK; ++i) {
    apk[i].x = __builtin_fabsf(wv0[i]);
    apk[i].y = __builtin_fabsf(wv1[i]);
  }

  v2f sp[9];
  sp[0] = splat(0.0f);
  v2f scs[8];
  v2f gb = splat(-1.0f);
  int gk0 = 0, gk1 = 0;
  Step<0>::run(apk, sp, scs, gb, gk0, gk1);

  // ---- epilogue: bit-identical to R0/R2 (proven absmax 0.0078125) ----
#pragma unroll
  for (int blk = 0; blk < 2; ++blk) {
    const float* wv = blk ? wv1 : wv0;
    int gk = blk ? gk1 : gk0;
    unsigned int bits = (unsigned int)g_pat[gk];

    float q[BLOCK];
#pragma unroll
    for (int i = 0; i < BLOCK; ++i) q[i] = ((bits >> i) & 1u) ? 3.0f : 1.0f;

    float p[BLOCK];
#pragma unroll
    for (int i = 0; i < BLOCK; ++i) p[i] = __builtin_fabsf(wv[i]) * q[i];
    float num = ((p[0] + p[1]) + (p[2] + p[3])) + ((p[4] + p[5]) + (p[6] + p[7]));

    int popc = __popc(bits);
    float normf = (float)(8 + (popc << 3));
    float scale = num / normf;              // IEEE CR f32 divide (once/block)

    float o[BLOCK];
#pragma unroll
    for (int i = 0; i < BLOCK; ++i) {
      float sg = (wv[i] > 0.0f) ? 1.0f : ((wv[i] < 0.0f) ? -1.0f : 0.0f);
      float deq = (scale * q[i]) * sg;
      o[i] = wv[i] + (deq - wv[i]);         // w + stop_gradient(deq - w)
    }

    float4 o0 = {o[0], o[1], o[2], o[3]};
    float4 o1 = {o[4], o[5], o[6], o[7]};
    float4* op = reinterpret_cast<float4*>(out) + (size_t)2 * (blk ? (t + half) : t);
    op[0] = o0;
    op[1] = o1;
  }
}

extern "C" void kernel_launch(void* const* d_in, const int* in_sizes, int n_in,
                              void* d_out, int out_size, void* d_ws, size_t ws_size,
                              hipStream_t stream) {
  (void)n_in; (void)d_ws; (void)ws_size; (void)out_size;
  const float* w = (const float*)d_in[0];
  float* out = (float*)d_out;
  int n = in_sizes[0];
  int nb = n / BLOCK;
  int half = nb >> 1;
  int threads = 256;
  int blocks = (half + threads - 1) / threads;
  _IQ2XSQuantWeight_12945031430379_kernel<<<blocks, threads, 0, stream>>>(w, out, nb);
}

// Round 5
// 85.990 us; speedup vs baseline: 1.0431x; 1.0431x over previous
//
#include <hip/hip_runtime.h>

#define BLOCK 8
#define NGRID 512

// ---------------------------------------------------------------------------
// Compile-time replication of
//   np.random.RandomState(0).choice(np.array([1.0,3.0],f32), size=(512,8))
// (MT19937 legacy scalar seeding, one 32-bit draw per value, value = draw&1).
// Bit i of pattern byte = element i: g[i] = bit ? 3.0f : 1.0f.
// Dedup (first occurrence) is argmax-neutral. kenc = 255 - dedup_index, so
// "ties -> max kenc" == numpy first-max. Scan order = bit-reversed ascending
// (maximizes shared low-bit spine prefixes); selection is order-independent.
// ---------------------------------------------------------------------------
struct Sched {
  int nd;                      // distinct patterns (~222)
  unsigned char kpat[256];     // kenc -> pattern byte (epilogue gather)
  unsigned char dfs_pat[256];  // scan ordinal -> pattern byte
  unsigned char dfs_ken[256];  // scan ordinal -> kenc
  unsigned char lowbit[256];   // ordinal -> lowest differing bit vs prev (0 for j=0)
  unsigned char csn[32];       // chunk -> member count (chunks of 8)
  unsigned char cslot[32][8];  // chunk, i -> slot (ordinal & 7), kenc-ascending
  unsigned char cken[32][8];   // chunk, i -> kenc,                kenc-ascending
};

constexpr unsigned char bitrev8c(unsigned v) {
  unsigned r = 0;
  for (int i = 0; i < 8; ++i) r |= ((v >> i) & 1u) << (7 - i);
  return (unsigned char)r;
}
constexpr int popcount8c(int v) {
  int p = 0;
  for (int i = 0; i < 8; ++i) p += (v >> i) & 1;
  return p;
}
constexpr int ctz8c(int v) {
  for (int i = 0; i < 8; ++i) if ((v >> i) & 1) return i;
  return 0;
}

constexpr Sched make_sched() {
  Sched t{};
  bool exists[256] = {};
  unsigned char kenc[256] = {};
  // --- MT19937, numpy legacy scalar seed 0 ---
  unsigned mt[624] = {};
  {
    unsigned s = 0u;
    for (int i = 0; i < 624; ++i) {
      mt[i] = s;
      s = 1812433253u * (s ^ (s >> 30)) + (unsigned)(i + 1);
    }
  }
  int pos = 624;
  int nd = 0;
  for (int j = 0; j < NGRID; ++j) {
    unsigned char b = 0;
    for (int i = 0; i < BLOCK; ++i) {
      if (pos == 624) {
        for (int k = 0; k < 624; ++k) {
          int k1 = (k + 1 < 624) ? k + 1 : 0;
          int k397 = (k + 397 < 624) ? k + 397 : k + 397 - 624;
          unsigned y = (mt[k] & 0x80000000u) | (mt[k1] & 0x7fffffffu);
          unsigned v = mt[k397] ^ (y >> 1);
          if (y & 1u) v ^= 0x9908b0dfu;
          mt[k] = v;
        }
        pos = 0;
      }
      unsigned y = mt[pos++];
      y ^= y >> 11;
      y ^= (y << 7) & 0x9d2c5680u;
      y ^= (y << 15) & 0xefc60000u;
      y ^= y >> 18;
      if (y & 1u) b |= (unsigned char)(1u << i);
    }
    if (!exists[b]) {
      exists[b] = true;
      kenc[b] = (unsigned char)(255 - nd);
      t.kpat[255 - nd] = b;
      ++nd;
    }
  }
  t.nd = nd;
  // --- scan order: bit-reversed ascending ---
  int m = 0;
  for (int r = 0; r < 256; ++r) {
    unsigned char b = bitrev8c((unsigned)r);
    if (exists[b]) {
      t.dfs_pat[m] = b;
      t.dfs_ken[m] = kenc[b];
      ++m;
    }
  }
  t.lowbit[0] = 0;
  for (int j = 1; j < nd; ++j)
    t.lowbit[j] = (unsigned char)ctz8c(t.dfs_pat[j] ^ t.dfs_pat[j - 1]);
  // --- chunks of 8, members sorted by kenc ascending (insertion sort) ---
  int nc = (nd + 7) / 8;
  for (int c = 0; c < nc; ++c) {
    int n = nd - 8 * c; if (n > 8) n = 8;
    t.csn[c] = (unsigned char)n;
    unsigned char sl[8] = {}, ke[8] = {};
    for (int i = 0; i < n; ++i) { sl[i] = (unsigned char)i; ke[i] = t.dfs_ken[8 * c + i]; }
    for (int i = 1; i < n; ++i) {
      unsigned char ks = ke[i], ss = sl[i];
      int p = i - 1;
      while (p >= 0 && ke[p] > ks) { ke[p + 1] = ke[p]; sl[p + 1] = sl[p]; --p; }
      ke[p + 1] = ks; sl[p + 1] = ss;
    }
    for (int i = 0; i < n; ++i) { t.cslot[c][i] = sl[i]; t.cken[c][i] = ke[i]; }
  }
  return t;
}

constexpr Sched SC = make_sched();
constexpr int ND = SC.nd;
static_assert(ND > 0 && ND <= 256, "sanity");

// chunk-local winner index -> kenc, packed 8 bytes into a u64 (compile time)
constexpr unsigned long long pack_klut(int c) {
  unsigned long long v = 0ull;
  for (int i = 0; i < 8; ++i)
    v |= (unsigned long long)SC.cken[c][i] << (8 * i);
  return v;
}

// epilogue gather table: kenc -> pattern byte (L1-resident)
__device__ __constant__ const unsigned char g_pat[256] = {
#define P1(z) SC.kpat[z]
#define P8(z) P1(z), P1(z+1), P1(z+2), P1(z+3), P1(z+4), P1(z+5), P1(z+6), P1(z+7)
#define P64(z) P8(z), P8(z+8), P8(z+16), P8(z+24), P8(z+32), P8(z+40), P8(z+48), P8(z+56)
    P64(0), P64(64), P64(128), P64(192)
#undef P64
#undef P8
#undef P1
};

// ---------------------------------------------------------------------------
// Scalar trie scan step, ordinal J. Spine sp[l+1] = dot over low l+1 bits'
// chain; leaf: sc = fl32(fl32(d*d)/norm) bit-identical to numpy (exact pow2
// scale or Markstein CR division). Scores buffered 8/chunk; chunk max via
// fmax tree (v_max3), winner via inline-const eq-scan in kenc-ascending
// order (last write = min original k), index->kenc via compile-time u64 LUT.
// ---------------------------------------------------------------------------
template <int J>
struct Step {
  static __device__ __forceinline__ void run(const float (&a)[BLOCK], float (&sp)[9],
                                             float (&scs)[8], float &gb, int &gk) {
    constexpr int pat = SC.dfs_pat[J];
    constexpr int p0 = (J == 0) ? 0 : SC.lowbit[J];
#pragma unroll
    for (int l = 0; l < 8; ++l) {
      if (l >= p0) {
        if ((pat >> l) & 1)
          sp[l + 1] = __builtin_fmaf(a[l], 3.0f, sp[l]);
        else
          sp[l + 1] = sp[l] + a[l];
      }
    }
    float d = sp[8];
    float dd = d * d;
    constexpr int pc = popcount8c(pat);
    float sc;
    if constexpr (pc == 0)      sc = dd * 0.125f;      // /8   exact
    else if constexpr (pc == 1) sc = dd * 0.0625f;     // /16  exact
    else if constexpr (pc == 3) sc = dd * 0.03125f;    // /32  exact
    else if constexpr (pc == 7) sc = dd * 0.015625f;   // /64  exact
    else {
      constexpr float nf = (float)(8 * (1 + pc));
      constexpr float rcf = 1.0f / nf;                 // RN reciprocal (compile time)
      float q0 = dd * rcf;
      float r = __builtin_fmaf(-nf, q0, dd);           // exact residual
      sc = __builtin_fmaf(r, rcf, q0);                 // Markstein: == fl32(dd/nf)
    }
    scs[J & 7] = sc;

    if constexpr (((J & 7) == 7) || (J == ND - 1)) {
      constexpr int c = J >> 3;
      constexpr int n = SC.csn[c];
      float cm;
      if constexpr (n == 8) {
        cm = __builtin_fmaxf(
            __builtin_fmaxf(__builtin_fmaxf(scs[0], scs[1]), __builtin_fmaxf(scs[2], scs[3])),
            __builtin_fmaxf(__builtin_fmaxf(scs[4], scs[5]), __builtin_fmaxf(scs[6], scs[7])));
      } else {
        cm = scs[0];
#pragma unroll
        for (int i = 1; i < n; ++i) cm = __builtin_fmaxf(cm, scs[i]);
      }
      int ck = 0;
#pragma unroll
      for (int i = 0; i < n; ++i)   // kenc ascending: last write = min original k
        ck = (scs[SC.cslot[c][i]] == cm) ? i : ck;     // i is an inline constant
      constexpr unsigned long long klut = pack_klut(c);
      int kenc = (int)((unsigned)(klut >> (ck << 3)) & 0xFFu);
      bool r = (cm > gb) || ((cm == gb) && (kenc > gk));
      gb = r ? cm : gb;
      gk = r ? kenc : gk;
    }
    if constexpr (J + 1 < ND) Step<J + 1>::run(a, sp, scs, gb, gk);
  }
};

__global__ __launch_bounds__(256, 8) void _IQ2XSQuantWeight_12945031430379_kernel(
    const float* __restrict__ w, float* __restrict__ out, int nb) {
  int t = blockIdx.x * blockDim.x + threadIdx.x;
  if (t >= nb) return;

  const float4* wp = reinterpret_cast<const float4*>(w) + (size_t)2 * t;
  float4 w0 = wp[0];
  float4 w1 = wp[1];
  float wv[BLOCK] = {w0.x, w0.y, w0.z, w0.w, w1.x, w1.y, w1.z, w1.w};

  float a[BLOCK];
#pragma unroll
  for (int i = 0; i < BLOCK; ++i) a[i] = __builtin_fabsf(wv[i]);

  float sp[9];
  sp[0] = 0.0f;
  float scs[8];
  float gb = -1.0f;
  int gk = 0;
  Step<0>::run(a, sp, scs, gb, gk);

  // ---- epilogue: bit-identical to R0/R2/R3 (proven absmax 0.0078125) ----
  unsigned int bits = (unsigned int)g_pat[gk];   // divergent 1-byte gather, L1

  float q[BLOCK];
#pragma unroll
  for (int i = 0; i < BLOCK; ++i) q[i] = ((bits >> i) & 1u) ? 3.0f : 1.0f;

  float p[BLOCK];
#pragma unroll
  for (int i = 0; i < BLOCK; ++i) p[i] = a[i] * q[i];
  float num = ((p[0] + p[1]) + (p[2] + p[3])) + ((p[4] + p[5]) + (p[6] + p[7]));

  int popc = __popc(bits);
  float normf = (float)(8 + (popc << 3));
  float scale = num / normf;                     // IEEE CR f32 divide (once)

  float o[BLOCK];
#pragma unroll
  for (int i = 0; i < BLOCK; ++i) {
    float sg = (wv[i] > 0.0f) ? 1.0f : ((wv[i] < 0.0f) ? -1.0f : 0.0f);
    float deq = (scale * q[i]) * sg;
    o[i] = wv[i] + (deq - wv[i]);                // w + stop_gradient(deq - w)
  }

  float4 o0 = {o[0], o[1], o[2], o[3]};
  float4 o1 = {o[4], o[5], o[6], o[7]};
  float4* op = reinterpret_cast<float4*>(out) + (size_t)2 * t;
  op[0] = o0;
  op[1] = o1;
}

extern "C" void kernel_launch(void* const* d_in, const int* in_sizes, int n_in,
                              void* d_out, int out_size, void* d_ws, size_t ws_size,
                              hipStream_t stream) {
  (void)n_in; (void)d_ws; (void)ws_size; (void)out_size;
  const float* w = (const float*)d_in[0];
  float* out = (float*)d_out;
  int n = in_sizes[0];
  int nb = n / BLOCK;
  int threads = 256;
  int blocks = (nb + threads - 1) / threads;
  _IQ2XSQuantWeight_12945031430379_kernel<<<blocks, threads, 0, stream>>>(w, out, nb);
}